// Round 1
// baseline (1378.579 us; speedup 1.0000x reference)
//
#include <hip/hip_runtime.h>
#include <math.h>

#define NN 50000
#define EE 640000
#define DD 128
#define LL 3
#define GGR 1024

// ---------------- degree / dinv ----------------
__global__ __launch_bounds__(256) void k_deg(const int* __restrict__ dst,
                                             float* __restrict__ deg) {
  int i = blockIdx.x * 256 + threadIdx.x;
  if (i < EE) atomicAdd(&deg[dst[i]], 1.0f);
  else if (i < EE + NN) atomicAdd(&deg[i - EE], 1.0f);  // self loops
}

__global__ __launch_bounds__(256) void k_dinv(float* __restrict__ deg) {
  int i = blockIdx.x * 256 + threadIdx.x;
  if (i < NN) deg[i] = rsqrtf(deg[i]);  // deg >= 1 (self loop) always
}

// ---------------- GEMM: Y[N,128] = X[N,128] @ W[128,128] ----------------
// 512 threads, 128-row tile. W (64KB) + X tile (64KB) in LDS.
// thread: c = feature quad (0..31), rg = row group (0..15), 8 rows each.
__global__ __launch_bounds__(512) void k_gemm(const float* __restrict__ X,
                                              const float* __restrict__ W,
                                              float* __restrict__ Y, int nrows) {
  __shared__ __align__(16) float Wl[DD * DD];
  __shared__ __align__(16) float Xl[128 * DD];
  const int t = threadIdx.x;
  for (int i = t; i < DD * DD; i += 512) Wl[i] = W[i];
  const int base = blockIdx.x * 128;
  for (int i = t; i < 128 * DD; i += 512) {
    int r = base + (i >> 7);
    Xl[i] = (r < nrows) ? X[(size_t)r * DD + (i & 127)] : 0.0f;
  }
  __syncthreads();

  const int c = t & 31;
  const int rg = t >> 5;  // 0..15
  float acc[8][4];
#pragma unroll
  for (int j = 0; j < 8; ++j)
#pragma unroll
    for (int q = 0; q < 4; ++q) acc[j][q] = 0.0f;

#pragma unroll 4
  for (int k = 0; k < DD; ++k) {
    float4 w4 = *reinterpret_cast<const float4*>(&Wl[k * DD + c * 4]);
#pragma unroll
    for (int j = 0; j < 8; ++j) {
      float xv = Xl[(rg * 8 + j) * DD + k];
      acc[j][0] = fmaf(xv, w4.x, acc[j][0]);
      acc[j][1] = fmaf(xv, w4.y, acc[j][1]);
      acc[j][2] = fmaf(xv, w4.z, acc[j][2]);
      acc[j][3] = fmaf(xv, w4.w, acc[j][3]);
    }
  }
#pragma unroll
  for (int j = 0; j < 8; ++j) {
    int r = base + rg * 8 + j;
    if (r < nrows) {
      float4 o = make_float4(acc[j][0], acc[j][1], acc[j][2], acc[j][3]);
      *reinterpret_cast<float4*>(&Y[(size_t)r * DD + c * 4]) = o;
    }
  }
}

// ---------------- edge aggregation (scatter-add) ----------------
// item e in [0, EE+NN): edges then self loops. 2 items per 256-thread block.
__global__ __launch_bounds__(256) void k_agg(const float* __restrict__ H,
                                             const int* __restrict__ src,
                                             const int* __restrict__ dst,
                                             const float* __restrict__ dinv,
                                             float* __restrict__ out) {
  int e = blockIdx.x * 2 + (threadIdx.x >> 7);
  if (e >= EE + NN) return;
  int f = threadIdx.x & 127;
  int s, d;
  if (e < EE) { s = src[e]; d = dst[e]; }
  else        { s = e - EE; d = s; }
  float w = dinv[s] * dinv[d];
  atomicAdd(&out[(size_t)d * DD + f], w * H[(size_t)s * DD + f]);
}

// ---------------- BatchNorm stats ----------------
__global__ __launch_bounds__(256) void k_bnstats(const float* __restrict__ H,
                                                 float* __restrict__ stats) {
  int f = threadIdx.x & 127;
  int rg = threadIdx.x >> 7;  // 0..1
  float s = 0.0f, s2 = 0.0f;
  for (int r = blockIdx.x * 2 + rg; r < NN; r += gridDim.x * 2) {
    float v = H[(size_t)r * DD + f];
    s += v;
    s2 = fmaf(v, v, s2);
  }
  __shared__ float red[2][128];
  if (rg == 1) { red[0][f] = s; red[1][f] = s2; }
  __syncthreads();
  if (rg == 0) {
    atomicAdd(&stats[f], s + red[0][f]);
    atomicAdd(&stats[DD + f], s2 + red[1][f]);
  }
}

// fold gamma/beta: musig[f] = scale, musig[128+f] = shift
__global__ void k_bnfin(const float* __restrict__ stats,
                        const float* __restrict__ gamma_,
                        const float* __restrict__ beta_,
                        float* __restrict__ musig) {
  int f = threadIdx.x;
  if (f >= DD) return;
  float mu = stats[f] * (1.0f / NN);
  float var = stats[DD + f] * (1.0f / NN) - mu * mu;
  float rsig = rsqrtf(var + 1e-5f);
  float sc = gamma_[f] * rsig;
  musig[f] = sc;
  musig[DD + f] = beta_[f] - sc * mu;
}

__device__ __forceinline__ float elu1(float x) {
  return x > 0.0f ? x : expm1f(x);
}

// scale/shift + ELU, in place, float4-vectorized
__global__ __launch_bounds__(256) void k_bnelu(float* __restrict__ H,
                                               const float* __restrict__ musig) {
  int i = blockIdx.x * 256 + threadIdx.x;  // over NN*32 float4s
  if (i >= NN * 32) return;
  int fq = i & 31;
  float4 v = reinterpret_cast<float4*>(H)[i];
  float4 sc = reinterpret_cast<const float4*>(musig)[fq];
  float4 sh = reinterpret_cast<const float4*>(musig)[32 + fq];
  v.x = elu1(fmaf(v.x, sc.x, sh.x));
  v.y = elu1(fmaf(v.y, sc.y, sh.y));
  v.z = elu1(fmaf(v.z, sc.z, sh.z));
  v.w = elu1(fmaf(v.w, sc.w, sh.w));
  reinterpret_cast<float4*>(H)[i] = v;
}

// ---------------- graph mean pooling ----------------
__global__ __launch_bounds__(256) void k_pool(const float* __restrict__ H,
                                              const int* __restrict__ bidx,
                                              float* __restrict__ out,
                                              float* __restrict__ cnts) {
  int n = blockIdx.x * 2 + (threadIdx.x >> 7);
  if (n >= NN) return;
  int f = threadIdx.x & 127;
  int g = bidx[n];
  atomicAdd(&out[(size_t)g * DD + f], H[(size_t)n * DD + f]);
  if (f == 0) atomicAdd(&cnts[g], 1.0f);
}

__global__ __launch_bounds__(256) void k_div(float* __restrict__ out,
                                             const float* __restrict__ cnts) {
  int i = blockIdx.x * 256 + threadIdx.x;
  if (i >= GGR * DD) return;
  out[i] = out[i] / fmaxf(cnts[i >> 7], 1.0f);
}

// ---------------- launch ----------------
extern "C" void kernel_launch(void* const* d_in, const int* in_sizes, int n_in,
                              void* d_out, int out_size, void* d_ws, size_t ws_size,
                              hipStream_t stream) {
  const float* x      = (const float*)d_in[0];
  const float* Ws     = (const float*)d_in[1];
  // d_in[2] = bs: cancels inside BatchNorm (uniform column shift) -> skipped
  const float* gammas = (const float*)d_in[3];
  const float* betas  = (const float*)d_in[4];
  const int*   ei     = (const int*)d_in[5];
  const int*   bidx   = (const int*)d_in[6];
  const int* srcp = ei;
  const int* dstp = ei + EE;

  float* bufA  = (float*)d_ws;                  // N*128
  float* bufB  = bufA + (size_t)NN * DD;        // N*128
  float* deg   = bufB + (size_t)NN * DD;        // N (becomes dinv in place)
  float* stats = deg + NN;                      // 256
  float* musig = stats + 256;                   // 256
  float* cnts  = musig + 256;                   // G
  float* out   = (float*)d_out;

  hipMemsetAsync(deg, 0, NN * sizeof(float), stream);
  k_deg<<<(EE + NN + 255) / 256, 256, 0, stream>>>(dstp, deg);
  k_dinv<<<(NN + 255) / 256, 256, 0, stream>>>(deg);

  const float* Xin = x;
  for (int l = 0; l < LL; ++l) {
    k_gemm<<<(NN + 127) / 128, 512, 0, stream>>>(Xin, Ws + (size_t)l * DD * DD,
                                                 bufB, NN);
    hipMemsetAsync(bufA, 0, (size_t)NN * DD * sizeof(float), stream);
    k_agg<<<(EE + NN + 1) / 2, 256, 0, stream>>>(bufB, srcp, dstp, deg, bufA);
    hipMemsetAsync(stats, 0, 256 * sizeof(float), stream);
    k_bnstats<<<256, 256, 0, stream>>>(bufA, stats);
    k_bnfin<<<1, 128, 0, stream>>>(stats, gammas + l * DD, betas + l * DD, musig);
    k_bnelu<<<(NN * 32 + 255) / 256, 256, 0, stream>>>(bufA, musig);
    Xin = bufA;
  }

  hipMemsetAsync(out, 0, (size_t)GGR * DD * sizeof(float), stream);
  hipMemsetAsync(cnts, 0, GGR * sizeof(float), stream);
  k_pool<<<(NN + 1) / 2, 256, 0, stream>>>(bufA, bidx, out, cnts);
  k_div<<<(GGR * DD + 255) / 256, 256, 0, stream>>>(out, cnts);
}

// Round 3
// 782.219 us; speedup vs baseline: 1.7624x; 1.7624x over previous
//
#include <hip/hip_runtime.h>
#include <math.h>

#define NN 50000
#define EE 640000
#define DD 128
#define LL 3
#define GGR 1024
#define SCHUNK 49  // 1024*49 = 50176 >= NN

// ---------------- CSR build ----------------
__global__ __launch_bounds__(256) void k_hist(const int* __restrict__ dst,
                                              int* __restrict__ cnt) {
  int e = blockIdx.x * 256 + threadIdx.x;
  if (e < EE) atomicAdd(&cnt[dst[e]], 1);
}

// exclusive scan of cnt[0..NN) -> rowstart, cursor; single block of 1024
__global__ __launch_bounds__(1024) void k_scan(const int* __restrict__ cnt,
                                               int* __restrict__ rowstart,
                                               int* __restrict__ cursor) {
  __shared__ int part[1024];
  int t = threadIdx.x;
  int beg = t * SCHUNK;
  int end = min(beg + SCHUNK, NN);
  int s = 0;
  for (int i = beg; i < end; ++i) s += cnt[i];
  part[t] = s;
  __syncthreads();
  for (int off = 1; off < 1024; off <<= 1) {
    int v = (t >= off) ? part[t - off] : 0;
    __syncthreads();
    part[t] += v;
    __syncthreads();
  }
  int run = (t == 0) ? 0 : part[t - 1];
  for (int i = beg; i < end; ++i) {
    rowstart[i] = run;
    cursor[i] = run;
    run += cnt[i];
  }
  if (t == 0) rowstart[NN] = EE;
}

__global__ __launch_bounds__(256) void k_dinv(const int* __restrict__ cnt,
                                              float* __restrict__ dinv) {
  int i = blockIdx.x * 256 + threadIdx.x;
  if (i < NN) dinv[i] = rsqrtf((float)(cnt[i] + 1));  // +1 self loop
}

__global__ __launch_bounds__(256) void k_scatter(const int* __restrict__ src,
                                                 const int* __restrict__ dst,
                                                 int* __restrict__ cursor,
                                                 int* __restrict__ csr_src) {
  int e = blockIdx.x * 256 + threadIdx.x;
  if (e < EE) {
    int pos = atomicAdd(&cursor[dst[e]], 1);
    csr_src[pos] = src[e];
  }
}

// ---------------- GEMM: Y[r] = act(X[r]) @ W, then * dinv[r] ----------------
// ACT: apply y = elu(x*sc[k] + sh[k]) to X elements while staging (prev layer's BN+ELU)
__device__ __forceinline__ float elu1(float x) {
  return x > 0.0f ? x : expm1f(x);
}

template <int ACT>
__global__ __launch_bounds__(512) void k_gemm(const float* __restrict__ X,
                                              const float* __restrict__ W,
                                              float* __restrict__ Y,
                                              const float* __restrict__ musig,
                                              const float* __restrict__ dinv) {
  __shared__ __align__(16) float Wl[DD * DD];
  __shared__ __align__(16) float Xl[128 * DD];
  __shared__ __align__(16) float scs[DD], shs[DD];
  const int t = threadIdx.x;
  if (ACT && t < DD) {
    scs[t] = musig[t];
    shs[t] = musig[DD + t];
  }
  const float4* W4 = reinterpret_cast<const float4*>(W);
  float4* Wl4 = reinterpret_cast<float4*>(Wl);
  for (int i = t; i < DD * 32; i += 512) Wl4[i] = W4[i];
  __syncthreads();  // scs/shs ready before X staging

  const int base = blockIdx.x * 128;
  const float4* X4 = reinterpret_cast<const float4*>(X);
  float4* Xl4 = reinterpret_cast<float4*>(Xl);
  const float4* sc4 = reinterpret_cast<const float4*>(scs);
  const float4* sh4 = reinterpret_cast<const float4*>(shs);
  for (int i = t; i < 128 * 32; i += 512) {
    int r = base + (i >> 5);
    int kq = i & 31;
    float4 v = make_float4(0.f, 0.f, 0.f, 0.f);
    if (r < NN) v = X4[(size_t)r * 32 + kq];
    if (ACT) {
      float4 sc = sc4[kq], sh = sh4[kq];
      v.x = elu1(fmaf(v.x, sc.x, sh.x));
      v.y = elu1(fmaf(v.y, sc.y, sh.y));
      v.z = elu1(fmaf(v.z, sc.z, sh.z));
      v.w = elu1(fmaf(v.w, sc.w, sh.w));
    }
    Xl4[i] = v;
  }
  __syncthreads();

  const int c = t & 31;
  const int rg = t >> 5;  // 0..15
  float acc[8][4];
#pragma unroll
  for (int j = 0; j < 8; ++j)
#pragma unroll
    for (int q = 0; q < 4; ++q) acc[j][q] = 0.0f;

#pragma unroll 4
  for (int k = 0; k < DD; ++k) {
    float4 w4 = *reinterpret_cast<const float4*>(&Wl[k * DD + c * 4]);
#pragma unroll
    for (int j = 0; j < 8; ++j) {
      float xv = Xl[(rg * 8 + j) * DD + k];
      acc[j][0] = fmaf(xv, w4.x, acc[j][0]);
      acc[j][1] = fmaf(xv, w4.y, acc[j][1]);
      acc[j][2] = fmaf(xv, w4.z, acc[j][2]);
      acc[j][3] = fmaf(xv, w4.w, acc[j][3]);
    }
  }
#pragma unroll
  for (int j = 0; j < 8; ++j) {
    int r = base + rg * 8 + j;
    if (r < NN) {
      float dv = dinv[r];
      float4 o = make_float4(acc[j][0] * dv, acc[j][1] * dv, acc[j][2] * dv,
                             acc[j][3] * dv);
      *reinterpret_cast<float4*>(&Y[(size_t)r * DD + c * 4]) = o;
    }
  }
}

// ---------------- CSR aggregation: out[d] = dinv[d]*(Hs[d] + sum Hs[src]) ---
__global__ __launch_bounds__(256) void k_agg_csr(const float* __restrict__ Hs,
                                                 const int* __restrict__ rowstart,
                                                 const int* __restrict__ csr_src,
                                                 const float* __restrict__ dinv,
                                                 float* __restrict__ out) {
  int d = blockIdx.x * 2 + (threadIdx.x >> 7);
  if (d >= NN) return;
  int f = threadIdx.x & 127;
  int beg = rowstart[d], end = rowstart[d + 1];
  float acc = Hs[(size_t)d * DD + f];  // self loop term
  int i = beg;
  for (; i + 1 < end; i += 2) {
    int s0 = csr_src[i], s1 = csr_src[i + 1];
    float a = Hs[(size_t)s0 * DD + f];
    float b = Hs[(size_t)s1 * DD + f];
    acc += a;
    acc += b;
  }
  if (i < end) acc += Hs[(size_t)csr_src[i] * DD + f];
  out[(size_t)d * DD + f] = acc * dinv[d];
}

// ---------------- BatchNorm stats ----------------
__global__ __launch_bounds__(256) void k_bnstats(const float* __restrict__ H,
                                                 float* __restrict__ stats) {
  int f = threadIdx.x & 127;
  int rg = threadIdx.x >> 7;  // 0..1
  float s = 0.0f, s2 = 0.0f;
  for (int r = blockIdx.x * 2 + rg; r < NN; r += gridDim.x * 2) {
    float v = H[(size_t)r * DD + f];
    s += v;
    s2 = fmaf(v, v, s2);
  }
  __shared__ float red[2][128];
  if (rg == 1) { red[0][f] = s; red[1][f] = s2; }
  __syncthreads();
  if (rg == 0) {
    atomicAdd(&stats[f], s + red[0][f]);
    atomicAdd(&stats[DD + f], s2 + red[1][f]);
  }
}

__global__ void k_bnfin(const float* __restrict__ stats,
                        const float* __restrict__ gamma_,
                        const float* __restrict__ beta_,
                        float* __restrict__ musig) {
  int f = threadIdx.x;
  if (f >= DD) return;
  float mu = stats[f] * (1.0f / NN);
  float var = stats[DD + f] * (1.0f / NN) - mu * mu;
  float rsig = rsqrtf(var + 1e-5f);
  float sc = gamma_[f] * rsig;
  musig[f] = sc;
  musig[DD + f] = beta_[f] - sc * mu;
}

// ---------------- pooling: apply BN+ELU of last layer, then mean ------------
__global__ __launch_bounds__(256) void k_pool(const float* __restrict__ H,
                                              const int* __restrict__ bidx,
                                              const float* __restrict__ musig,
                                              float* __restrict__ out,
                                              float* __restrict__ cnts) {
  int n = blockIdx.x * 2 + (threadIdx.x >> 7);
  if (n >= NN) return;
  int f = threadIdx.x & 127;
  float v = elu1(fmaf(H[(size_t)n * DD + f], musig[f], musig[DD + f]));
  int g = bidx[n];
  atomicAdd(&out[(size_t)g * DD + f], v);
  if (f == 0) atomicAdd(&cnts[g], 1.0f);
}

__global__ __launch_bounds__(256) void k_div(float* __restrict__ out,
                                             const float* __restrict__ cnts) {
  int i = blockIdx.x * 256 + threadIdx.x;
  if (i >= GGR * DD) return;
  out[i] = out[i] / fmaxf(cnts[i >> 7], 1.0f);
}

// ---------------- launch ----------------
extern "C" void kernel_launch(void* const* d_in, const int* in_sizes, int n_in,
                              void* d_out, int out_size, void* d_ws, size_t ws_size,
                              hipStream_t stream) {
  const float* x      = (const float*)d_in[0];
  const float* Ws     = (const float*)d_in[1];
  // d_in[2] = bs: uniform column shift cancels inside BatchNorm -> skipped
  const float* gammas = (const float*)d_in[3];
  const float* betas  = (const float*)d_in[4];
  const int*   ei     = (const int*)d_in[5];
  const int*   bidx   = (const int*)d_in[6];
  const int* srcp = ei;
  const int* dstp = ei + EE;

  float* bufA  = (float*)d_ws;                   // N*128
  float* bufB  = bufA + (size_t)NN * DD;         // N*128
  float* dinv  = bufB + (size_t)NN * DD;         // N
  float* stats = dinv + NN;                      // 256
  float* musig = stats + 256;                    // 256
  float* cnts  = musig + 256;                    // G
  int* cnt      = (int*)(cnts + GGR);            // N
  int* rowstart = cnt + NN;                      // N+1
  int* cursor   = rowstart + NN + 1;             // N
  int* csr_src  = cursor + NN;                   // E
  float* out = (float*)d_out;

  // CSR build (once per call, reused for all 3 layers)
  hipMemsetAsync(cnt, 0, NN * sizeof(int), stream);
  k_hist<<<(EE + 255) / 256, 256, 0, stream>>>(dstp, cnt);
  k_scan<<<1, 1024, 0, stream>>>(cnt, rowstart, cursor);
  k_dinv<<<(NN + 255) / 256, 256, 0, stream>>>(cnt, dinv);
  k_scatter<<<(EE + 255) / 256, 256, 0, stream>>>(srcp, dstp, cursor, csr_src);

  const float* Xin = x;
  for (int l = 0; l < LL; ++l) {
    const float* Wl = Ws + (size_t)l * DD * DD;
    if (l == 0)
      k_gemm<0><<<(NN + 127) / 128, 512, 0, stream>>>(Xin, Wl, bufB, musig, dinv);
    else
      k_gemm<1><<<(NN + 127) / 128, 512, 0, stream>>>(Xin, Wl, bufB, musig, dinv);
    k_agg_csr<<<(NN + 1) / 2, 256, 0, stream>>>(bufB, rowstart, csr_src, dinv, bufA);
    hipMemsetAsync(stats, 0, 256 * sizeof(float), stream);
    k_bnstats<<<256, 256, 0, stream>>>(bufA, stats);
    k_bnfin<<<1, 128, 0, stream>>>(stats, gammas + l * DD, betas + l * DD, musig);
    Xin = bufA;
  }

  hipMemsetAsync(out, 0, (size_t)GGR * DD * sizeof(float), stream);
  hipMemsetAsync(cnts, 0, GGR * sizeof(float), stream);
  k_pool<<<(NN + 1) / 2, 256, 0, stream>>>(bufA, bidx, musig, out, cnts);
  k_div<<<(GGR * DD + 255) / 256, 256, 0, stream>>>(out, cnts);
}

// Round 6
// 677.201 us; speedup vs baseline: 2.0357x; 1.1551x over previous
//
#include <hip/hip_runtime.h>
#include <math.h>

#define NN 50000
#define EE 640000
#define DD 128
#define LL 3
#define GGR 1024
#define NBLK 196  // 196*256 = 50176 >= NN

// ---------------- CSR build ----------------
__global__ __launch_bounds__(256) void k_hist(const int* __restrict__ dst,
                                              int* __restrict__ cnt) {
  int e = blockIdx.x * 256 + threadIdx.x;
  if (e < EE) atomicAdd(&cnt[dst[e]], 1);
}

// hierarchical exclusive scan: pass 1 — per-block sums
__global__ __launch_bounds__(256) void k_scan1(const int* __restrict__ cnt,
                                               int* __restrict__ part) {
  int i = blockIdx.x * 256 + threadIdx.x;
  int v = (i < NN) ? cnt[i] : 0;
  __shared__ int red[256];
  red[threadIdx.x] = v;
  __syncthreads();
  for (int off = 128; off > 0; off >>= 1) {
    if (threadIdx.x < off) red[threadIdx.x] += red[threadIdx.x + off];
    __syncthreads();
  }
  if (threadIdx.x == 0) part[blockIdx.x] = red[0];
}

// pass 2 — scan the 196 partials (one small block)
__global__ __launch_bounds__(256) void k_scan2(int* __restrict__ part) {
  __shared__ int a[256];
  int t = threadIdx.x;
  int own = (t < NBLK) ? part[t] : 0;
  a[t] = own;
  __syncthreads();
  for (int off = 1; off < 256; off <<= 1) {
    int v = (t >= off) ? a[t - off] : 0;
    __syncthreads();
    a[t] += v;
    __syncthreads();
  }
  if (t < NBLK) part[t] = a[t] - own;  // exclusive
}

// pass 3 — block-local exclusive scan + offset; also writes cursor & dinv
__global__ __launch_bounds__(256) void k_scan3(const int* __restrict__ cnt,
                                               const int* __restrict__ part,
                                               int* __restrict__ rowstart,
                                               int* __restrict__ cursor,
                                               float* __restrict__ dinv) {
  int t = threadIdx.x;
  int i = blockIdx.x * 256 + t;
  int c = (i < NN) ? cnt[i] : 0;
  __shared__ int a[256];
  a[t] = c;
  __syncthreads();
  for (int off = 1; off < 256; off <<= 1) {
    int v = (t >= off) ? a[t - off] : 0;
    __syncthreads();
    a[t] += v;
    __syncthreads();
  }
  int excl = a[t] - c + part[blockIdx.x];
  if (i < NN) {
    rowstart[i] = excl;
    cursor[i] = excl;
    dinv[i] = rsqrtf((float)(c + 1));  // +1 self loop
  }
  if (i == 0) rowstart[NN] = EE;
}

__global__ __launch_bounds__(256) void k_scatter(const int* __restrict__ src,
                                                 const int* __restrict__ dst,
                                                 int* __restrict__ cursor,
                                                 int* __restrict__ csr_src) {
  int e = blockIdx.x * 256 + threadIdx.x;
  if (e < EE) {
    int pos = atomicAdd(&cursor[dst[e]], 1);
    csr_src[pos] = src[e];
  }
}

// ---------------- GEMM: Y[r] = act(X[r]) @ W, then * dinv[r] ----------------
__device__ __forceinline__ float elu1(float x) {
  return x > 0.0f ? x : expm1f(x);
}

template <int ACT>
__global__ __launch_bounds__(512) void k_gemm(const float* __restrict__ X,
                                              const float* __restrict__ W,
                                              float* __restrict__ Y,
                                              const float* __restrict__ musig,
                                              const float* __restrict__ dinv) {
  __shared__ __align__(16) float Wl[DD * DD];
  __shared__ __align__(16) float Xl[128 * DD];
  __shared__ __align__(16) float scs[DD], shs[DD];
  const int t = threadIdx.x;
  if (ACT && t < DD) {
    scs[t] = musig[t];
    shs[t] = musig[DD + t];
  }
  const float4* W4 = reinterpret_cast<const float4*>(W);
  float4* Wl4 = reinterpret_cast<float4*>(Wl);
  for (int i = t; i < DD * 32; i += 512) Wl4[i] = W4[i];
  __syncthreads();  // scs/shs ready before X staging

  const int base = blockIdx.x * 128;
  const float4* X4 = reinterpret_cast<const float4*>(X);
  float4* Xl4 = reinterpret_cast<float4*>(Xl);
  const float4* sc4 = reinterpret_cast<const float4*>(scs);
  const float4* sh4 = reinterpret_cast<const float4*>(shs);
  for (int i = t; i < 128 * 32; i += 512) {
    int r = base + (i >> 5);
    int kq = i & 31;
    float4 v = make_float4(0.f, 0.f, 0.f, 0.f);
    if (r < NN) v = X4[(size_t)r * 32 + kq];
    if (ACT) {
      float4 sc = sc4[kq], sh = sh4[kq];
      v.x = elu1(fmaf(v.x, sc.x, sh.x));
      v.y = elu1(fmaf(v.y, sc.y, sh.y));
      v.z = elu1(fmaf(v.z, sc.z, sh.z));
      v.w = elu1(fmaf(v.w, sc.w, sh.w));
    }
    Xl4[i] = v;
  }
  __syncthreads();

  const int c = t & 31;
  const int rg = t >> 5;  // 0..15
  float acc[8][4];
#pragma unroll
  for (int j = 0; j < 8; ++j)
#pragma unroll
    for (int q = 0; q < 4; ++q) acc[j][q] = 0.0f;

#pragma unroll 4
  for (int k = 0; k < DD; ++k) {
    float4 w4 = *reinterpret_cast<const float4*>(&Wl[k * DD + c * 4]);
#pragma unroll
    for (int j = 0; j < 8; ++j) {
      float xv = Xl[(rg * 8 + j) * DD + k];
      acc[j][0] = fmaf(xv, w4.x, acc[j][0]);
      acc[j][1] = fmaf(xv, w4.y, acc[j][1]);
      acc[j][2] = fmaf(xv, w4.z, acc[j][2]);
      acc[j][3] = fmaf(xv, w4.w, acc[j][3]);
    }
  }
#pragma unroll
  for (int j = 0; j < 8; ++j) {
    int r = base + rg * 8 + j;
    if (r < NN) {
      float dv = dinv[r];
      float4 o = make_float4(acc[j][0] * dv, acc[j][1] * dv, acc[j][2] * dv,
                             acc[j][3] * dv);
      *reinterpret_cast<float4*>(&Y[(size_t)r * DD + c * 4]) = o;
    }
  }
}

// ---------------- CSR aggregation: out[d] = dinv[d]*(Hs[d] + sum Hs[src]) ---
__global__ __launch_bounds__(256) void k_agg_csr(const float* __restrict__ Hs,
                                                 const int* __restrict__ rowstart,
                                                 const int* __restrict__ csr_src,
                                                 const float* __restrict__ dinv,
                                                 float* __restrict__ out) {
  int d = blockIdx.x * 2 + (threadIdx.x >> 7);
  if (d >= NN) return;
  int f = threadIdx.x & 127;
  int beg = rowstart[d], end = rowstart[d + 1];
  float acc = Hs[(size_t)d * DD + f];  // self loop term
  int i = beg;
  for (; i + 1 < end; i += 2) {
    int s0 = csr_src[i], s1 = csr_src[i + 1];
    float a = Hs[(size_t)s0 * DD + f];
    float b = Hs[(size_t)s1 * DD + f];
    acc += a;
    acc += b;
  }
  if (i < end) acc += Hs[(size_t)csr_src[i] * DD + f];
  out[(size_t)d * DD + f] = acc * dinv[d];
}

// ---------------- BatchNorm stats ----------------
__global__ __launch_bounds__(256) void k_bnstats(const float* __restrict__ H,
                                                 float* __restrict__ stats) {
  int f = threadIdx.x & 127;
  int rg = threadIdx.x >> 7;  // 0..1
  float s = 0.0f, s2 = 0.0f;
  for (int r = blockIdx.x * 2 + rg; r < NN; r += gridDim.x * 2) {
    float v = H[(size_t)r * DD + f];
    s += v;
    s2 = fmaf(v, v, s2);
  }
  __shared__ float red[2][128];
  if (rg == 1) { red[0][f] = s; red[1][f] = s2; }
  __syncthreads();
  if (rg == 0) {
    atomicAdd(&stats[f], s + red[0][f]);
    atomicAdd(&stats[DD + f], s2 + red[1][f]);
  }
}

__global__ void k_bnfin(const float* __restrict__ stats,
                        const float* __restrict__ gamma_,
                        const float* __restrict__ beta_,
                        float* __restrict__ musig) {
  int f = threadIdx.x;
  if (f >= DD) return;
  float mu = stats[f] * (1.0f / NN);
  float var = stats[DD + f] * (1.0f / NN) - mu * mu;
  float rsig = rsqrtf(var + 1e-5f);
  float sc = gamma_[f] * rsig;
  musig[f] = sc;
  musig[DD + f] = beta_[f] - sc * mu;
}

// ---------------- pooling: apply BN+ELU of last layer, then mean ------------
__global__ __launch_bounds__(256) void k_pool(const float* __restrict__ H,
                                              const int* __restrict__ bidx,
                                              const float* __restrict__ musig,
                                              float* __restrict__ out,
                                              float* __restrict__ cnts) {
  int n = blockIdx.x * 2 + (threadIdx.x >> 7);
  if (n >= NN) return;
  int f = threadIdx.x & 127;
  float v = elu1(fmaf(H[(size_t)n * DD + f], musig[f], musig[DD + f]));
  int g = bidx[n];
  atomicAdd(&out[(size_t)g * DD + f], v);
  if (f == 0) atomicAdd(&cnts[g], 1.0f);
}

__global__ __launch_bounds__(256) void k_div(float* __restrict__ out,
                                             const float* __restrict__ cnts) {
  int i = blockIdx.x * 256 + threadIdx.x;
  if (i >= GGR * DD) return;
  out[i] = out[i] / fmaxf(cnts[i >> 7], 1.0f);
}

// ---------------- launch ----------------
extern "C" void kernel_launch(void* const* d_in, const int* in_sizes, int n_in,
                              void* d_out, int out_size, void* d_ws, size_t ws_size,
                              hipStream_t stream) {
  const float* x      = (const float*)d_in[0];
  const float* Ws     = (const float*)d_in[1];
  // d_in[2] = bs: uniform column shift cancels inside BatchNorm -> skipped
  const float* gammas = (const float*)d_in[3];
  const float* betas  = (const float*)d_in[4];
  const int*   ei     = (const int*)d_in[5];
  const int*   bidx   = (const int*)d_in[6];
  const int* srcp = ei;
  const int* dstp = ei + EE;

  float* bufA  = (float*)d_ws;                   // N*128
  float* bufB  = bufA + (size_t)NN * DD;         // N*128
  float* dinv  = bufB + (size_t)NN * DD;         // N
  float* stats = dinv + NN;                      // 256
  float* musig = stats + 256;                    // 256
  float* cnts  = musig + 256;                    // G
  int* cnt      = (int*)(cnts + GGR);            // N
  int* rowstart = cnt + NN;                      // N+1
  int* cursor   = rowstart + NN + 1;             // N
  int* csr_src  = cursor + NN;                   // E
  int* part     = csr_src + EE;                  // NBLK
  float* out = (float*)d_out;

  // CSR build (once per call, reused for all 3 layers)
  hipMemsetAsync(cnt, 0, NN * sizeof(int), stream);
  k_hist<<<(EE + 255) / 256, 256, 0, stream>>>(dstp, cnt);
  k_scan1<<<NBLK, 256, 0, stream>>>(cnt, part);
  k_scan2<<<1, 256, 0, stream>>>(part);
  k_scan3<<<NBLK, 256, 0, stream>>>(cnt, part, rowstart, cursor, dinv);
  k_scatter<<<(EE + 255) / 256, 256, 0, stream>>>(srcp, dstp, cursor, csr_src);

  const float* Xin = x;
  for (int l = 0; l < LL; ++l) {
    const float* Wl = Ws + (size_t)l * DD * DD;
    if (l == 0)
      k_gemm<0><<<(NN + 127) / 128, 512, 0, stream>>>(Xin, Wl, bufB, musig, dinv);
    else
      k_gemm<1><<<(NN + 127) / 128, 512, 0, stream>>>(Xin, Wl, bufB, musig, dinv);
    k_agg_csr<<<(NN + 1) / 2, 256, 0, stream>>>(bufB, rowstart, csr_src, dinv, bufA);
    hipMemsetAsync(stats, 0, 256 * sizeof(float), stream);
    k_bnstats<<<256, 256, 0, stream>>>(bufA, stats);
    k_bnfin<<<1, 128, 0, stream>>>(stats, gammas + l * DD, betas + l * DD, musig);
    Xin = bufA;
  }

  hipMemsetAsync(out, 0, (size_t)GGR * DD * sizeof(float), stream);
  hipMemsetAsync(cnts, 0, GGR * sizeof(float), stream);
  k_pool<<<(NN + 1) / 2, 256, 0, stream>>>(bufA, bidx, musig, out, cnts);
  k_div<<<(GGR * DD + 255) / 256, 256, 0, stream>>>(out, cnts);
}

// Round 8
// 511.556 us; speedup vs baseline: 2.6949x; 1.3238x over previous
//
#include <hip/hip_runtime.h>
#include <hip/hip_fp16.h>
#include <math.h>

#define NN 50000
#define EE 640000
#define DD 128
#define LL 3
#define GGR 1024
#define NBLK 196  // 196*256 = 50176 >= NN

// ---------------- CSR build ----------------
__global__ __launch_bounds__(256) void k_hist(const int* __restrict__ dst,
                                              int* __restrict__ cnt) {
  int e = blockIdx.x * 256 + threadIdx.x;
  if (e < EE) atomicAdd(&cnt[dst[e]], 1);
}

__global__ __launch_bounds__(256) void k_scan1(const int* __restrict__ cnt,
                                               int* __restrict__ part) {
  int i = blockIdx.x * 256 + threadIdx.x;
  int v = (i < NN) ? cnt[i] : 0;
  __shared__ int red[256];
  red[threadIdx.x] = v;
  __syncthreads();
  for (int off = 128; off > 0; off >>= 1) {
    if (threadIdx.x < off) red[threadIdx.x] += red[threadIdx.x + off];
    __syncthreads();
  }
  if (threadIdx.x == 0) part[blockIdx.x] = red[0];
}

__global__ __launch_bounds__(256) void k_scan2(int* __restrict__ part) {
  __shared__ int a[256];
  int t = threadIdx.x;
  int own = (t < NBLK) ? part[t] : 0;
  a[t] = own;
  __syncthreads();
  for (int off = 1; off < 256; off <<= 1) {
    int v = (t >= off) ? a[t - off] : 0;
    __syncthreads();
    a[t] += v;
    __syncthreads();
  }
  if (t < NBLK) part[t] = a[t] - own;  // exclusive
}

__global__ __launch_bounds__(256) void k_scan3(const int* __restrict__ cnt,
                                               const int* __restrict__ part,
                                               int* __restrict__ rowstart,
                                               int* __restrict__ cursor,
                                               float* __restrict__ dinv) {
  int t = threadIdx.x;
  int i = blockIdx.x * 256 + t;
  int c = (i < NN) ? cnt[i] : 0;
  __shared__ int a[256];
  a[t] = c;
  __syncthreads();
  for (int off = 1; off < 256; off <<= 1) {
    int v = (t >= off) ? a[t - off] : 0;
    __syncthreads();
    a[t] += v;
    __syncthreads();
  }
  int excl = a[t] - c + part[blockIdx.x];
  if (i < NN) {
    rowstart[i] = excl;
    cursor[i] = excl;
    dinv[i] = rsqrtf((float)(c + 1));  // +1 self loop
  }
  if (i == 0) rowstart[NN] = EE;
}

__global__ __launch_bounds__(256) void k_scatter(const int* __restrict__ src,
                                                 const int* __restrict__ dst,
                                                 int* __restrict__ cursor,
                                                 int* __restrict__ csr_src) {
  int e = blockIdx.x * 256 + threadIdx.x;
  if (e < EE) {
    int pos = atomicAdd(&cursor[dst[e]], 1);
    csr_src[pos] = src[e];
  }
}

// ---------------- GEMM: Yh[r] = fp16( (act(X[r]) @ W) * dinv[r] ) ----------
__device__ __forceinline__ float elu1(float x) {
  return x > 0.0f ? x : expm1f(x);
}

template <int ACT>
__global__ __launch_bounds__(512) void k_gemm(const float* __restrict__ X,
                                              const float* __restrict__ W,
                                              __half* __restrict__ Yh,
                                              const float* __restrict__ musig,
                                              const float* __restrict__ dinv) {
  __shared__ __align__(16) float Wl[DD * DD];
  __shared__ __align__(16) float Xl[128 * DD];
  __shared__ __align__(16) float scs[DD], shs[DD];
  const int t = threadIdx.x;
  if (ACT && t < DD) {
    scs[t] = musig[t];
    shs[t] = musig[DD + t];
  }
  const float4* W4 = reinterpret_cast<const float4*>(W);
  float4* Wl4 = reinterpret_cast<float4*>(Wl);
  for (int i = t; i < DD * 32; i += 512) Wl4[i] = W4[i];
  __syncthreads();  // scs/shs ready before X staging

  const int base = blockIdx.x * 128;
  const float4* X4 = reinterpret_cast<const float4*>(X);
  float4* Xl4 = reinterpret_cast<float4*>(Xl);
  const float4* sc4 = reinterpret_cast<const float4*>(scs);
  const float4* sh4 = reinterpret_cast<const float4*>(shs);
  for (int i = t; i < 128 * 32; i += 512) {
    int r = base + (i >> 5);
    int kq = i & 31;
    float4 v = make_float4(0.f, 0.f, 0.f, 0.f);
    if (r < NN) v = X4[(size_t)r * 32 + kq];
    if (ACT) {
      float4 sc = sc4[kq], sh = sh4[kq];
      v.x = elu1(fmaf(v.x, sc.x, sh.x));
      v.y = elu1(fmaf(v.y, sc.y, sh.y));
      v.z = elu1(fmaf(v.z, sc.z, sh.z));
      v.w = elu1(fmaf(v.w, sc.w, sh.w));
    }
    Xl4[i] = v;
  }
  __syncthreads();

  const int c = t & 31;
  const int rg = t >> 5;  // 0..15
  float acc[8][4];
#pragma unroll
  for (int j = 0; j < 8; ++j)
#pragma unroll
    for (int q = 0; q < 4; ++q) acc[j][q] = 0.0f;

#pragma unroll 4
  for (int k = 0; k < DD; ++k) {
    float4 w4 = *reinterpret_cast<const float4*>(&Wl[k * DD + c * 4]);
#pragma unroll
    for (int j = 0; j < 8; ++j) {
      float xv = Xl[(rg * 8 + j) * DD + k];
      acc[j][0] = fmaf(xv, w4.x, acc[j][0]);
      acc[j][1] = fmaf(xv, w4.y, acc[j][1]);
      acc[j][2] = fmaf(xv, w4.z, acc[j][2]);
      acc[j][3] = fmaf(xv, w4.w, acc[j][3]);
    }
  }
#pragma unroll
  for (int j = 0; j < 8; ++j) {
    int r = base + rg * 8 + j;
    if (r < NN) {
      float dv = dinv[r];
      __half2 h0 = __floats2half2_rn(acc[j][0] * dv, acc[j][1] * dv);
      __half2 h1 = __floats2half2_rn(acc[j][2] * dv, acc[j][3] * dv);
      __half2* y2 = reinterpret_cast<__half2*>(Yh + (size_t)r * DD + c * 4);
      y2[0] = h0;
      y2[1] = h1;
    }
  }
}

// ---- CSR aggregation: out[d] = dinv[d]*(Hs[d] + sum Hs[src]), Hs in fp16 ---
// one 64-lane wave per dst row (lane covers 2 features via half2), 4 rows/block
__global__ __launch_bounds__(256) void k_agg_csr(const __half2* __restrict__ Hs,
                                                 const int* __restrict__ rowstart,
                                                 const int* __restrict__ csr_src,
                                                 const float* __restrict__ dinv,
                                                 float* __restrict__ out) {
  int d = blockIdx.x * 4 + (threadIdx.x >> 6);
  if (d >= NN) return;
  int lane = threadIdx.x & 63;
  int beg = rowstart[d], end = rowstart[d + 1];

  float2 s = __half22float2(Hs[(size_t)d * 64 + lane]);  // self loop
  float a0x = s.x, a0y = s.y;
  float a1x = 0.f, a1y = 0.f, a2x = 0.f, a2y = 0.f, a3x = 0.f, a3y = 0.f;

  int i = beg;
  for (; i + 3 < end; i += 4) {
    int s0 = csr_src[i], s1 = csr_src[i + 1];
    int s2 = csr_src[i + 2], s3 = csr_src[i + 3];
    float2 v0 = __half22float2(Hs[(size_t)s0 * 64 + lane]);
    float2 v1 = __half22float2(Hs[(size_t)s1 * 64 + lane]);
    float2 v2 = __half22float2(Hs[(size_t)s2 * 64 + lane]);
    float2 v3 = __half22float2(Hs[(size_t)s3 * 64 + lane]);
    a0x += v0.x; a0y += v0.y;
    a1x += v1.x; a1y += v1.y;
    a2x += v2.x; a2y += v2.y;
    a3x += v3.x; a3y += v3.y;
  }
  for (; i < end; ++i) {
    float2 v = __half22float2(Hs[(size_t)csr_src[i] * 64 + lane]);
    a0x += v.x; a0y += v.y;
  }
  float dv = dinv[d];
  float2 r;
  r.x = (a0x + a1x + a2x + a3x) * dv;
  r.y = (a0y + a1y + a2y + a3y) * dv;
  *reinterpret_cast<float2*>(&out[(size_t)d * DD + lane * 2]) = r;
}

// ---------------- BatchNorm stats ----------------
__global__ __launch_bounds__(256) void k_bnstats(const float* __restrict__ H,
                                                 float* __restrict__ stats) {
  int f = threadIdx.x & 127;
  int rg = threadIdx.x >> 7;  // 0..1
  float s = 0.0f, s2 = 0.0f;
  for (int r = blockIdx.x * 2 + rg; r < NN; r += gridDim.x * 2) {
    float v = H[(size_t)r * DD + f];
    s += v;
    s2 = fmaf(v, v, s2);
  }
  __shared__ float red[2][128];
  if (rg == 1) { red[0][f] = s; red[1][f] = s2; }
  __syncthreads();
  if (rg == 0) {
    atomicAdd(&stats[f], s + red[0][f]);
    atomicAdd(&stats[DD + f], s2 + red[1][f]);
  }
}

__global__ void k_bnfin(const float* __restrict__ stats,
                        const float* __restrict__ gamma_,
                        const float* __restrict__ beta_,
                        float* __restrict__ musig) {
  int f = threadIdx.x;
  if (f >= DD) return;
  float mu = stats[f] * (1.0f / NN);
  float var = stats[DD + f] * (1.0f / NN) - mu * mu;
  float rsig = rsqrtf(var + 1e-5f);
  float sc = gamma_[f] * rsig;
  musig[f] = sc;
  musig[DD + f] = beta_[f] - sc * mu;
}

// ---- pooling: BN+ELU of last layer fused; run-length segmented atomics -----
// batch_idx is SORTED: accumulate per-graph runs in registers, flush once per
// run. Block covers 128 consecutive nodes; each 128-thread half takes 64.
__global__ __launch_bounds__(256) void k_pool(const float* __restrict__ H,
                                              const int* __restrict__ bidx,
                                              const float* __restrict__ musig,
                                              float* __restrict__ out,
                                              float* __restrict__ cnts) {
  int f = threadIdx.x & 127;
  int h = threadIdx.x >> 7;
  int n0 = blockIdx.x * 128 + h * 64;
  if (n0 >= NN) return;
  int n1 = min(n0 + 64, NN);
  float sc = musig[f], sh = musig[DD + f];
  int gcur = bidx[n0];
  float racc = 0.0f, rcnt = 0.0f;
  for (int n = n0; n < n1; ++n) {
    int g = bidx[n];
    if (g != gcur) {
      atomicAdd(&out[(size_t)gcur * DD + f], racc);
      if (f == 0) atomicAdd(&cnts[gcur], rcnt);
      gcur = g;
      racc = 0.0f;
      rcnt = 0.0f;
    }
    float v = elu1(fmaf(H[(size_t)n * DD + f], sc, sh));
    racc += v;
    rcnt += 1.0f;
  }
  atomicAdd(&out[(size_t)gcur * DD + f], racc);
  if (f == 0) atomicAdd(&cnts[gcur], rcnt);
}

__global__ __launch_bounds__(256) void k_div(float* __restrict__ out,
                                             const float* __restrict__ cnts) {
  int i = blockIdx.x * 256 + threadIdx.x;
  if (i >= GGR * DD) return;
  out[i] = out[i] / fmaxf(cnts[i >> 7], 1.0f);
}

// ---------------- launch ----------------
extern "C" void kernel_launch(void* const* d_in, const int* in_sizes, int n_in,
                              void* d_out, int out_size, void* d_ws, size_t ws_size,
                              hipStream_t stream) {
  const float* x      = (const float*)d_in[0];
  const float* Ws     = (const float*)d_in[1];
  // d_in[2] = bs: uniform column shift cancels inside BatchNorm -> skipped
  const float* gammas = (const float*)d_in[3];
  const float* betas  = (const float*)d_in[4];
  const int*   ei     = (const int*)d_in[5];
  const int*   bidx   = (const int*)d_in[6];
  const int* srcp = ei;
  const int* dstp = ei + EE;

  float* bufA  = (float*)d_ws;                   // N*128 f32 (agg out)
  float* bufBf = bufA + (size_t)NN * DD;         // N*128 (fp16 staging area)
  __half* bufB = (__half*)bufBf;
  float* dinv  = bufBf + (size_t)NN * DD;        // N
  float* stats = dinv + NN;                      // 256
  float* musig = stats + 256;                    // 256
  float* cnts  = musig + 256;                    // G
  int* cnt      = (int*)(cnts + GGR);            // N
  int* rowstart = cnt + NN;                      // N+1
  int* cursor   = rowstart + NN + 1;             // N
  int* csr_src  = cursor + NN;                   // E
  int* part     = csr_src + EE;                  // NBLK
  float* out = (float*)d_out;

  // CSR build (once per call, reused for all 3 layers)
  hipMemsetAsync(cnt, 0, NN * sizeof(int), stream);
  k_hist<<<(EE + 255) / 256, 256, 0, stream>>>(dstp, cnt);
  k_scan1<<<NBLK, 256, 0, stream>>>(cnt, part);
  k_scan2<<<1, 256, 0, stream>>>(part);
  k_scan3<<<NBLK, 256, 0, stream>>>(cnt, part, rowstart, cursor, dinv);
  k_scatter<<<(EE + 255) / 256, 256, 0, stream>>>(srcp, dstp, cursor, csr_src);

  const float* Xin = x;
  for (int l = 0; l < LL; ++l) {
    const float* Wl = Ws + (size_t)l * DD * DD;
    if (l == 0)
      k_gemm<0><<<(NN + 127) / 128, 512, 0, stream>>>(Xin, Wl, bufB, musig, dinv);
    else
      k_gemm<1><<<(NN + 127) / 128, 512, 0, stream>>>(Xin, Wl, bufB, musig, dinv);
    k_agg_csr<<<(NN + 3) / 4, 256, 0, stream>>>((const __half2*)bufB, rowstart,
                                                csr_src, dinv, bufA);
    hipMemsetAsync(stats, 0, 256 * sizeof(float), stream);
    k_bnstats<<<256, 256, 0, stream>>>(bufA, stats);
    k_bnfin<<<1, 128, 0, stream>>>(stats, gammas + l * DD, betas + l * DD, musig);
    Xin = bufA;
  }

  hipMemsetAsync(out, 0, (size_t)GGR * DD * sizeof(float), stream);
  hipMemsetAsync(cnts, 0, GGR * sizeof(float), stream);
  k_pool<<<(NN + 127) / 128, 256, 0, stream>>>(bufA, bidx, musig, out, cnts);
  k_div<<<(GGR * DD + 255) / 256, 256, 0, stream>>>(out, cnts);
}

// Round 10
// 459.923 us; speedup vs baseline: 2.9974x; 1.1123x over previous
//
#include <hip/hip_runtime.h>
#include <hip/hip_fp16.h>
#include <math.h>

#define NN 50000
#define EE 640000
#define DD 128
#define LL 3
#define GGR 1024
#define NBLK 196  // 196*256 = 50176 >= NN

typedef _Float16 half8 __attribute__((ext_vector_type(8)));
typedef float f32x4 __attribute__((ext_vector_type(4)));

// ---------------- CSR build ----------------
__global__ __launch_bounds__(256) void k_hist(const int* __restrict__ dst,
                                              int* __restrict__ cnt) {
  int e = blockIdx.x * 256 + threadIdx.x;
  if (e < EE) atomicAdd(&cnt[dst[e]], 1);
}

__global__ __launch_bounds__(256) void k_scan1(const int* __restrict__ cnt,
                                               int* __restrict__ part) {
  int i = blockIdx.x * 256 + threadIdx.x;
  int v = (i < NN) ? cnt[i] : 0;
  __shared__ int red[256];
  red[threadIdx.x] = v;
  __syncthreads();
  for (int off = 128; off > 0; off >>= 1) {
    if (threadIdx.x < off) red[threadIdx.x] += red[threadIdx.x + off];
    __syncthreads();
  }
  if (threadIdx.x == 0) part[blockIdx.x] = red[0];
}

__global__ __launch_bounds__(256) void k_scan2(int* __restrict__ part) {
  __shared__ int a[256];
  int t = threadIdx.x;
  int own = (t < NBLK) ? part[t] : 0;
  a[t] = own;
  __syncthreads();
  for (int off = 1; off < 256; off <<= 1) {
    int v = (t >= off) ? a[t - off] : 0;
    __syncthreads();
    a[t] += v;
    __syncthreads();
  }
  if (t < NBLK) part[t] = a[t] - own;  // exclusive
}

__global__ __launch_bounds__(256) void k_scan3(const int* __restrict__ cnt,
                                               const int* __restrict__ part,
                                               int* __restrict__ rowstart,
                                               int* __restrict__ cursor,
                                               float* __restrict__ dinv) {
  int t = threadIdx.x;
  int i = blockIdx.x * 256 + t;
  int c = (i < NN) ? cnt[i] : 0;
  __shared__ int a[256];
  a[t] = c;
  __syncthreads();
  for (int off = 1; off < 256; off <<= 1) {
    int v = (t >= off) ? a[t - off] : 0;
    __syncthreads();
    a[t] += v;
    __syncthreads();
  }
  int excl = a[t] - c + part[blockIdx.x];
  if (i < NN) {
    rowstart[i] = excl;
    cursor[i] = excl;
    dinv[i] = rsqrtf((float)(c + 1));  // +1 self loop
  }
  if (i == 0) rowstart[NN] = EE;
}

__global__ __launch_bounds__(256) void k_scatter(const int* __restrict__ src,
                                                 const int* __restrict__ dst,
                                                 int* __restrict__ cursor,
                                                 int* __restrict__ csr_src) {
  int e = blockIdx.x * 256 + threadIdx.x;
  if (e < EE) {
    int pos = atomicAdd(&cursor[dst[e]], 1);
    csr_src[pos] = src[e];
  }
}

// ---- W prep: transpose + fp16 hi/lo split: Wt[l][col][k] ----
__global__ __launch_bounds__(256) void k_wprep(const float* __restrict__ Ws,
                                               __half* __restrict__ Wth,
                                               __half* __restrict__ Wtl) {
  int i = blockIdx.x * 256 + threadIdx.x;
  if (i >= LL * DD * DD) return;
  int l = i >> 14;  // / (128*128)
  int rem = i & 16383;
  int k = rem >> 7, col = rem & 127;
  float w = Ws[i];
  __half hi = __float2half(w);
  __half lo = __float2half(w - __half2float(hi));
  size_t o = (size_t)l * DD * DD + (size_t)col * DD + k;
  Wth[o] = hi;
  Wtl[o] = lo;
}

// ---------------- GEMM via MFMA (fp16 split precision) ----------------
// Yh[r] = fp16( (dinv[r] * act(X[r])) @ W ), act = prev layer's BN+ELU.
// 512 thr = 8 waves; block tile 128 rows x 128 cols; K=128 in 4 MFMA steps.
// LDS tiles XOR-swizzled: byte_in_row ^= ((row&7)<<4) on write AND read.
__device__ __forceinline__ float elu1(float x) {
  return x > 0.0f ? x : expm1f(x);
}

template <int ACT>
__global__ __launch_bounds__(512) void k_gemm(const float* __restrict__ X,
                                              const __half* __restrict__ Wth,
                                              const __half* __restrict__ Wtl,
                                              __half* __restrict__ Yh,
                                              const float* __restrict__ musig,
                                              const float* __restrict__ dinv) {
  __shared__ __align__(16) __half Wh_s[DD * DD];   // [col][k] hi
  __shared__ __align__(16) __half Wl_s[DD * DD];   // [col][k] lo
  __shared__ __align__(16) __half Xh_s[128 * DD];  // [row][k] hi
  __shared__ __align__(16) __half Xl_s[128 * DD];  // [row][k] lo
  __shared__ float scs[DD], shs[DD];
  const int t = threadIdx.x;
  if (ACT && t < DD) {
    scs[t] = musig[t];
    shs[t] = musig[DD + t];
  }
  char* WhB = (char*)Wh_s;
  char* WlB = (char*)Wl_s;
  for (int ch = t; ch < DD * DD / 8; ch += 512) {
    int col = ch >> 4;
    int k0 = (ch & 15) << 3;
    half8 h = *reinterpret_cast<const half8*>(Wth + (size_t)col * DD + k0);
    half8 l = *reinterpret_cast<const half8*>(Wtl + (size_t)col * DD + k0);
    int off = col * 256 + ((k0 * 2) ^ ((col & 7) << 4));
    *reinterpret_cast<half8*>(WhB + off) = h;
    *reinterpret_cast<half8*>(WlB + off) = l;
  }
  __syncthreads();  // scs/shs visible before X staging

  const int base = blockIdx.x * 128;
  const float4* X4 = reinterpret_cast<const float4*>(X);
  char* XhB = (char*)Xh_s;
  char* XlB = (char*)Xl_s;
  for (int i = t; i < 128 * 32; i += 512) {
    int rl = i >> 5;
    int r = base + rl;
    int kq = i & 31;
    float4 v = make_float4(0.f, 0.f, 0.f, 0.f);
    float dv = 0.0f;
    if (r < NN) {
      v = X4[(size_t)r * 32 + kq];
      dv = dinv[r];
    }
    if (ACT) {
      float4 sc = reinterpret_cast<const float4*>(scs)[kq];
      float4 sh = reinterpret_cast<const float4*>(shs)[kq];
      v.x = elu1(fmaf(v.x, sc.x, sh.x));
      v.y = elu1(fmaf(v.y, sc.y, sh.y));
      v.z = elu1(fmaf(v.z, sc.z, sh.z));
      v.w = elu1(fmaf(v.w, sc.w, sh.w));
    }
    v.x *= dv; v.y *= dv; v.z *= dv; v.w *= dv;
    __half2 h0 = __floats2half2_rn(v.x, v.y);
    __half2 h1 = __floats2half2_rn(v.z, v.w);
    __half2 l0 = __floats2half2_rn(v.x - __low2float(h0), v.y - __high2float(h0));
    __half2 l1 = __floats2half2_rn(v.z - __low2float(h1), v.w - __high2float(h1));
    int off = rl * 256 + ((kq * 8) ^ ((rl & 7) << 4));
    *reinterpret_cast<__half2*>(XhB + off) = h0;
    *reinterpret_cast<__half2*>(XhB + off + 4) = h1;
    *reinterpret_cast<__half2*>(XlB + off) = l0;
    *reinterpret_cast<__half2*>(XlB + off + 4) = l1;
  }
  __syncthreads();

  // fragment layout (AMD lab-notes): A: row=lane%16, k=8*(lane/16)+j
  // B: col=lane%16, k=8*(lane/16)+j (W stored [col][k]); D: row=4*(lane/16)+j
  const int w = t >> 6, l = t & 63;
  const int lr = l & 15, lg = l >> 4;
  const int arow = w * 16 + lr;
  const int aswz = (arow & 7) << 4;
  f32x4 acc[8];
#pragma unroll
  for (int c = 0; c < 8; ++c) acc[c] = (f32x4){0.f, 0.f, 0.f, 0.f};
#pragma unroll
  for (int kk = 0; kk < 4; ++kk) {
    int kbyte = kk * 64 + lg * 16;
    half8 Ah = *reinterpret_cast<half8*>(XhB + arow * 256 + (kbyte ^ aswz));
    half8 Al = *reinterpret_cast<half8*>(XlB + arow * 256 + (kbyte ^ aswz));
#pragma unroll
    for (int c = 0; c < 8; ++c) {
      int col = c * 16 + lr;
      int boff = col * 256 + (kbyte ^ ((col & 7) << 4));
      half8 Bh = *reinterpret_cast<half8*>(WhB + boff);
      half8 Bl = *reinterpret_cast<half8*>(WlB + boff);
      acc[c] = __builtin_amdgcn_mfma_f32_16x16x32_f16(Ah, Bh, acc[c], 0, 0, 0);
      acc[c] = __builtin_amdgcn_mfma_f32_16x16x32_f16(Al, Bh, acc[c], 0, 0, 0);
      acc[c] = __builtin_amdgcn_mfma_f32_16x16x32_f16(Ah, Bl, acc[c], 0, 0, 0);
    }
  }
#pragma unroll
  for (int c = 0; c < 8; ++c) {
#pragma unroll
    for (int j = 0; j < 4; ++j) {
      int row = base + w * 16 + lg * 4 + j;
      if (row < NN)
        Yh[(size_t)row * DD + c * 16 + lr] = __float2half(acc[c][j]);
    }
  }
}

// ---- CSR aggregation: out[d] = dinv[d]*(Hs[d] + sum Hs[src]), Hs in fp16 ---
__global__ __launch_bounds__(256) void k_agg_csr(const __half2* __restrict__ Hs,
                                                 const int* __restrict__ rowstart,
                                                 const int* __restrict__ csr_src,
                                                 const float* __restrict__ dinv,
                                                 float* __restrict__ out) {
  int d = blockIdx.x * 4 + (threadIdx.x >> 6);
  if (d >= NN) return;
  int lane = threadIdx.x & 63;
  int beg = rowstart[d], end = rowstart[d + 1];

  float2 s = __half22float2(Hs[(size_t)d * 64 + lane]);  // self loop
  float a0x = s.x, a0y = s.y;
  float a1x = 0.f, a1y = 0.f, a2x = 0.f, a2y = 0.f, a3x = 0.f, a3y = 0.f;

  int i = beg;
  for (; i + 3 < end; i += 4) {
    int s0 = csr_src[i], s1 = csr_src[i + 1];
    int s2 = csr_src[i + 2], s3 = csr_src[i + 3];
    float2 v0 = __half22float2(Hs[(size_t)s0 * 64 + lane]);
    float2 v1 = __half22float2(Hs[(size_t)s1 * 64 + lane]);
    float2 v2 = __half22float2(Hs[(size_t)s2 * 64 + lane]);
    float2 v3 = __half22float2(Hs[(size_t)s3 * 64 + lane]);
    a0x += v0.x; a0y += v0.y;
    a1x += v1.x; a1y += v1.y;
    a2x += v2.x; a2y += v2.y;
    a3x += v3.x; a3y += v3.y;
  }
  for (; i < end; ++i) {
    float2 v = __half22float2(Hs[(size_t)csr_src[i] * 64 + lane]);
    a0x += v.x; a0y += v.y;
  }
  float dv = dinv[d];
  float2 r;
  r.x = (a0x + a1x + a2x + a3x) * dv;
  r.y = (a0y + a1y + a2y + a3y) * dv;
  *reinterpret_cast<float2*>(&out[(size_t)d * DD + lane * 2]) = r;
}

// ---------------- BatchNorm stats ----------------
__global__ __launch_bounds__(256) void k_bnstats(const float* __restrict__ H,
                                                 float* __restrict__ stats) {
  int f = threadIdx.x & 127;
  int rg = threadIdx.x >> 7;  // 0..1
  float s = 0.0f, s2 = 0.0f;
  for (int r = blockIdx.x * 2 + rg; r < NN; r += gridDim.x * 2) {
    float v = H[(size_t)r * DD + f];
    s += v;
    s2 = fmaf(v, v, s2);
  }
  __shared__ float red[2][128];
  if (rg == 1) { red[0][f] = s; red[1][f] = s2; }
  __syncthreads();
  if (rg == 0) {
    atomicAdd(&stats[f], s + red[0][f]);
    atomicAdd(&stats[DD + f], s2 + red[1][f]);
  }
}

__global__ void k_bnfin(const float* __restrict__ stats,
                        const float* __restrict__ gamma_,
                        const float* __restrict__ beta_,
                        float* __restrict__ musig) {
  int f = threadIdx.x;
  if (f >= DD) return;
  float mu = stats[f] * (1.0f / NN);
  float var = stats[DD + f] * (1.0f / NN) - mu * mu;
  float rsig = rsqrtf(var + 1e-5f);
  float sc = gamma_[f] * rsig;
  musig[f] = sc;
  musig[DD + f] = beta_[f] - sc * mu;
}

// ---- pooling: BN+ELU of last layer fused; run-length segmented atomics -----
__global__ __launch_bounds__(256) void k_pool(const float* __restrict__ H,
                                              const int* __restrict__ bidx,
                                              const float* __restrict__ musig,
                                              float* __restrict__ out,
                                              float* __restrict__ cnts) {
  int f = threadIdx.x & 127;
  int h = threadIdx.x >> 7;
  int n0 = blockIdx.x * 128 + h * 64;
  if (n0 >= NN) return;
  int n1 = min(n0 + 64, NN);
  float sc = musig[f], sh = musig[DD + f];
  int gcur = bidx[n0];
  float racc = 0.0f, rcnt = 0.0f;
  for (int n = n0; n < n1; ++n) {
    int g = bidx[n];
    if (g != gcur) {
      atomicAdd(&out[(size_t)gcur * DD + f], racc);
      if (f == 0) atomicAdd(&cnts[gcur], rcnt);
      gcur = g;
      racc = 0.0f;
      rcnt = 0.0f;
    }
    float v = elu1(fmaf(H[(size_t)n * DD + f], sc, sh));
    racc += v;
    rcnt += 1.0f;
  }
  atomicAdd(&out[(size_t)gcur * DD + f], racc);
  if (f == 0) atomicAdd(&cnts[gcur], rcnt);
}

__global__ __launch_bounds__(256) void k_div(float* __restrict__ out,
                                             const float* __restrict__ cnts) {
  int i = blockIdx.x * 256 + threadIdx.x;
  if (i >= GGR * DD) return;
  out[i] = out[i] / fmaxf(cnts[i >> 7], 1.0f);
}

// ---------------- launch ----------------
extern "C" void kernel_launch(void* const* d_in, const int* in_sizes, int n_in,
                              void* d_out, int out_size, void* d_ws, size_t ws_size,
                              hipStream_t stream) {
  const float* x      = (const float*)d_in[0];
  const float* Ws     = (const float*)d_in[1];
  // d_in[2] = bs: uniform column shift cancels inside BatchNorm -> skipped
  const float* gammas = (const float*)d_in[3];
  const float* betas  = (const float*)d_in[4];
  const int*   ei     = (const int*)d_in[5];
  const int*   bidx   = (const int*)d_in[6];
  const int* srcp = ei;
  const int* dstp = ei + EE;

  __half* Wth  = (__half*)d_ws;                  // 3*128*128 fp16 (hi), 16B-aligned
  __half* Wtl  = Wth + (size_t)LL * DD * DD;     // 3*128*128 fp16 (lo)
  float* bufA  = (float*)(Wtl + (size_t)LL * DD * DD);  // N*128 f32 (agg out)
  float* bufBf = bufA + (size_t)NN * DD;         // N*128 (fp16 staging area)
  __half* bufB = (__half*)bufBf;
  float* dinv  = bufBf + (size_t)NN * DD;        // N
  float* stats = dinv + NN;                      // 256
  float* musig = stats + 256;                    // 256
  float* cnts  = musig + 256;                    // G
  int* cnt      = (int*)(cnts + GGR);            // N
  int* rowstart = cnt + NN;                      // N+1
  int* cursor   = rowstart + NN + 1;             // N
  int* csr_src  = cursor + NN;                   // E
  int* part     = csr_src + EE;                  // NBLK
  float* out = (float*)d_out;

  // W transpose + split (once per call)
  k_wprep<<<(LL * DD * DD + 255) / 256, 256, 0, stream>>>(Ws, Wth, Wtl);

  // CSR build (once per call, reused for all 3 layers)
  hipMemsetAsync(cnt, 0, NN * sizeof(int), stream);
  k_hist<<<(EE + 255) / 256, 256, 0, stream>>>(dstp, cnt);
  k_scan1<<<NBLK, 256, 0, stream>>>(cnt, part);
  k_scan2<<<1, 256, 0, stream>>>(part);
  k_scan3<<<NBLK, 256, 0, stream>>>(cnt, part, rowstart, cursor, dinv);
  k_scatter<<<(EE + 255) / 256, 256, 0, stream>>>(srcp, dstp, cursor, csr_src);

  const float* Xin = x;
  for (int l = 0; l < LL; ++l) {
    const __half* Wh = Wth + (size_t)l * DD * DD;
    const __half* Wl = Wtl + (size_t)l * DD * DD;
    if (l == 0)
      k_gemm<0><<<(NN + 127) / 128, 512, 0, stream>>>(Xin, Wh, Wl, bufB, musig, dinv);
    else
      k_gemm<1><<<(NN + 127) / 128, 512, 0, stream>>>(Xin, Wh, Wl, bufB, musig, dinv);
    k_agg_csr<<<(NN + 3) / 4, 256, 0, stream>>>((const __half2*)bufB, rowstart,
                                                csr_src, dinv, bufA);
    hipMemsetAsync(stats, 0, 256 * sizeof(float), stream);
    k_bnstats<<<256, 256, 0, stream>>>(bufA, stats);
    k_bnfin<<<1, 128, 0, stream>>>(stats, gammas + l * DD, betas + l * DD, musig);
    Xin = bufA;
  }

  hipMemsetAsync(out, 0, (size_t)GGR * DD * sizeof(float), stream);
  hipMemsetAsync(cnts, 0, GGR * sizeof(float), stream);
  k_pool<<<(NN + 127) / 128, 256, 0, stream>>>(bufA, bidx, musig, out, cnts);
  k_div<<<(GGR * DD + 255) / 256, 256, 0, stream>>>(out, cnts);
}